// Round 15
// baseline (115.676 us; speedup 1.0000x reference)
//
#include <hip/hip_runtime.h>

// ============================================================================
// AttentionWithSpatial: x@Wqkv -> masked/biased 4-head attention -> @Wout+b
// b=4, n=2048, dim=256, heads=4, dhead=64, scale=0.125
//
// R14 post-mortem: 7th structure in the 54-65us band; nothing saturated ->
// per-iter serial chain at 2 waves/SIMD. R15: T15 software pipeline on R14's
// exact numerics: per tile t, stages S(QK^T+bias+pmax-tree) / F(m-update,
// exp2, pack, exchange) / P(rescale+PV). Issue order F(t); S(t+1); P(t) --
// S/P MFMAs overlap F's VALU. K/bias reg-dbuf 1 tile ahead; V per-iter.
// Barrier-free, QBLK=32/wave, KV-split=2, Q hi-only. All layouts unchanged.
// k_prep/k_qkv/k_comb/k_out identical to passing R14.
// ============================================================================

#define B_   4
#define N_   2048
#define H_   4
#define DH_  64
#define DIMX 256
#define M_   (B_*N_)   // 8192

#define LOG2E  1.4426950408889634f
#define NEGINF (-1e30f)
#define DEFER_THR 8.0f

typedef __attribute__((ext_vector_type(8))) short short8;
typedef __attribute__((ext_vector_type(4))) float f32x4;
typedef unsigned short u16;
typedef unsigned int   u32;

#define MFMA16(a,b,c) __builtin_amdgcn_mfma_f32_16x16x32_bf16((a),(b),(c),0,0,0)

__device__ __forceinline__ u16 f2bf(float f) {
  u32 u = __builtin_bit_cast(u32, f);
  u += 0x7fffu + ((u >> 16) & 1u);   // RNE
  return (u16)(u >> 16);
}
__device__ __forceinline__ float bf2f(u16 h) {
  u32 u = ((u32)h) << 16;
  return __builtin_bit_cast(float, u);
}
__device__ __forceinline__ void split2(float f, u16* hi, u16* lo) {
  u16 h = f2bf(f);
  *hi = h;
  *lo = f2bf(f - bf2f(h));
}
__device__ __forceinline__ u32 cvtpk(float lo, float hi) {
  u32 r;
  asm("v_cvt_pk_bf16_f32 %0, %1, %2" : "=v"(r) : "v"(lo), "v"(hi));
  return r;
}

struct u16v4 { u16 a, b, c, d; };
struct u16v8 { u16 v[8]; };

// ---------------------------------------------------------------------------
// Kernel 1 (fused prep):
//  blocks [0,4096): bias prefuse, TWO adjacent-kt records per thread
//  blocks [4096,7168): x -> xh/xl split; Wqkv/Wout transpose+split
// ---------------------------------------------------------------------------
__global__ __launch_bounds__(256) void k_prep(
    const int* __restrict__ mask, const float* __restrict__ spat,
    const float* __restrict__ x, const float* __restrict__ wq,
    const float* __restrict__ wo,
    u16* __restrict__ biasF,
    u16* __restrict__ xh, u16* __restrict__ xl,
    u16* __restrict__ wqh, u16* __restrict__ wql,
    u16* __restrict__ woh, u16* __restrict__ wol)
{
  if (blockIdx.x < 4096) {
    const int rr = blockIdx.x * 256 + threadIdx.x;    // [0, 1048576)
    const int lane = rr & 63;
    const int kt2 = (rr >> 6) & 31;                   // kt pair
    const int qt = (rr >> 11) & 127;
    const int b  = rr >> 18;
    const int kt = kt2 * 2;
    const int ln = lane & 15, hb = lane >> 4;
    const int q  = qt * 16 + ln;
    const int c0 = kt * 32 + hb * 4;
    const int base = (b * N_ + q) * N_ + c0;

    int4   m[4];
    float4 s[4];
#pragma unroll
    for (int i = 0; i < 4; ++i) {
      m[i] = *(const int4*)&mask[base + i * 16];
      s[i] = *(const float4*)&spat[base + i * 16];
    }

    const float NB = -10000.0f;
    const size_t r0 = ((size_t)((b * 128 + qt) * 64 + kt) * 64 + lane) * 8;
#pragma unroll
    for (int g = 0; g < 2; ++g) {      // record kt+g
      u16v8 o;
      const int4   ma = m[g * 2], mb = m[g * 2 + 1];
      const float4 sa = s[g * 2], sb = s[g * 2 + 1];
      o.v[0] = __builtin_bit_cast(u16, (_Float16)(ma.x ? sa.x * LOG2E : NB));
      o.v[1] = __builtin_bit_cast(u16, (_Float16)(ma.y ? sa.y * LOG2E : NB));
      o.v[2] = __builtin_bit_cast(u16, (_Float16)(ma.z ? sa.z * LOG2E : NB));
      o.v[3] = __builtin_bit_cast(u16, (_Float16)(ma.w ? sa.w * LOG2E : NB));
      o.v[4] = __builtin_bit_cast(u16, (_Float16)(mb.x ? sb.x * LOG2E : NB));
      o.v[5] = __builtin_bit_cast(u16, (_Float16)(mb.y ? sb.y * LOG2E : NB));
      o.v[6] = __builtin_bit_cast(u16, (_Float16)(mb.z ? sb.z * LOG2E : NB));
      o.v[7] = __builtin_bit_cast(u16, (_Float16)(mb.w ? sb.w * LOG2E : NB));
      *(u16v8*)&biasF[r0 + (size_t)g * 512] = o;
    }
    return;
  }

  const int NX4 = (M_ * DIMX) / 4;  // 524288
  const int NWQ = 768 * 256;        // 196608
  const int NWO = 256 * 256;        // 65536
  int i = (blockIdx.x - 4096) * 256 + threadIdx.x;
  if (i < NX4) {
    const float4 v = ((const float4*)x)[i];
    u16v4 hv, lv;
    split2(v.x, &hv.a, &lv.a);
    split2(v.y, &hv.b, &lv.b);
    split2(v.z, &hv.c, &lv.c);
    split2(v.w, &hv.d, &lv.d);
    ((u16v4*)xh)[i] = hv;
    ((u16v4*)xl)[i] = lv;
  } else if (i < NX4 + NWQ) {
    int j = i - NX4;
    int c = j >> 8, k = j & 255;            // out layout [c][k]
    split2(wq[k * 768 + c], &wqh[j], &wql[j]);
  } else if (i < NX4 + NWQ + NWO) {
    int j = i - NX4 - NWQ;
    int c = j >> 8, k = j & 255;
    split2(wo[k * 256 + c], &woh[j], &wol[j]);
  }
}

// ---------------------------------------------------------------------------
// Kernel 2: QKV GEMM, LDS-staged. M=8192, N=768, K=256. grid (12, 64).
// B tile (hi+lo) staged once in 64KB LDS, XOR-swizzled; 2 M-subtiles/block;
// 16 A loads upfront per subtile; MFMA fed from LDS.
// ---------------------------------------------------------------------------
__global__ __launch_bounds__(256) void k_qkv(
    const u16* __restrict__ xh, const u16* __restrict__ xl,
    const u16* __restrict__ wh, const u16* __restrict__ wl,
    u16* __restrict__ qh, u16* __restrict__ ql,
    u16* __restrict__ kf, u16* __restrict__ vf)
{
  __shared__ __align__(16) u16 BhL[64 * 256];   // 32 KB, swizzled
  __shared__ __align__(16) u16 BlL[64 * 256];   // 32 KB

  const int tid = threadIdx.x;
  const int w = tid >> 6, lane = tid & 63;
  const int ln = lane & 15, hb = lane >> 4;
  const int colb = blockIdx.x * 64;

  // ---- stage B (hi+lo) into LDS, reg-batched, coalesced ----
  {
    short8 sb[16];
#pragma unroll
    for (int it = 0; it < 8; ++it) {
      const int c = it * 8 + (tid >> 5), k8 = tid & 31;
      sb[it]     = *(const short8*)&wh[(colb + c) * 256 + k8 * 8];
      sb[8 + it] = *(const short8*)&wl[(colb + c) * 256 + k8 * 8];
    }
#pragma unroll
    for (int it = 0; it < 8; ++it) {
      const int c = it * 8 + (tid >> 5), k8 = tid & 31;
      const int le = c * 256 + ((k8 * 8) ^ ((c & 7) << 3));
      *(short8*)&BhL[le] = sb[it];
      *(short8*)&BlL[le] = sb[8 + it];
    }
  }
  __syncthreads();

#pragma unroll
  for (int st = 0; st < 2; ++st) {
    const int mtile = blockIdx.y * 2 + st;
    const int arow = mtile * 64 + w * 16 + ln;

    short8 a_h8[8], a_l8[8];
#pragma unroll
    for (int ks = 0; ks < 8; ++ks) {
      a_h8[ks] = *(const short8*)&xh[arow * 256 + ks * 32 + hb * 8];
      a_l8[ks] = *(const short8*)&xl[arow * 256 + ks * 32 + hb * 8];
    }

    f32x4 acc[4] = {};
#pragma unroll
    for (int ks = 0; ks < 8; ++ks) {
      const int k0 = ks * 32 + hb * 8;
#pragma unroll
      for (int j = 0; j < 4; ++j) {
        const int c = j * 16 + ln;
        const int le = c * 256 + (k0 ^ ((c & 7) << 3));
        const short8 b_h = *(const short8*)&BhL[le];
        const short8 b_l = *(const short8*)&BlL[le];
        acc[j] = MFMA16(a_h8[ks], b_h, acc[j]);
        acc[j] = MFMA16(a_l8[ks], b_h, acc[j]);
        acc[j] = MFMA16(a_h8[ks], b_l, acc[j]);
      }
    }

    const int mbase = mtile * 64 + w * 16 + hb * 4;
#pragma unroll
    for (int j = 0; j < 4; ++j) {
      const int c = colb + j * 16 + ln;
      const int which = c >> 8;        // 0=q 1=k 2=v
      const int hd = c & 255;
      const int hh = hd >> 6, d = hd & 63;
#pragma unroll
      for (int r = 0; r < 4; ++r) {
        const int m = mbase + r;
        const int bb = m >> 11, nn = m & 2047;
        const int bh = bb * H_ + hh;
        float v = acc[j][r];
        if (which == 0) {
          const int off = (bh * N_ + nn) * DH_ + d;
          v *= (0.125f * LOG2E);                 // scale + exp2-domain fold
          split2(v, &qh[off], &ql[off]);
        } else if (which == 1) {
          const int ktile = nn >> 5, jj = (nn >> 4) & 1, lnn = nn & 15;
          const int kc = d >> 5, hbb = (d >> 3) & 3, e = d & 7;
          const int off = (bh * 64 + ktile) * 2048 + (kc * 2 + jj) * 512
                        + (hbb * 16 + lnn) * 8 + e;
          kf[off] = f2bf(v);
        } else {
          const int ktile = nn >> 5, hbb = (nn >> 3) & 3, e = nn & 7;
          const int j2 = d >> 4, lnn = d & 15;
          const int off = (bh * 64 + ktile) * 2048 + j2 * 512
                        + (hbb * 16 + lnn) * 8 + e;
          vf[off] = f2bf(v);
        }
      }
    }
  }
}

// ---------------------------------------------------------------------------
// Kernel 3: flash attention partials, KV-split=2, BARRIER-FREE, QBLK=32,
// T15 software pipeline. grid 512: bid -> half, bh, qp as R14.
// Stages per tile t: S = QK^T+bias-init+pmax-tree (indep of m-chain);
// F = m-update, exp2, pack, P-exchange; P = O-rescale + PV.
// Issue order: F(t); S(t+1); P(t) -- S/P MFMA overlap F VALU.
// ---------------------------------------------------------------------------
__global__ __launch_bounds__(256) void k_attn(
    const u16* __restrict__ qhg,
    const u16* __restrict__ kfg, const u16* __restrict__ vfg,
    const u16* __restrict__ biasF,
    float* __restrict__ Op0, float* __restrict__ Op1,
    float* __restrict__ MP, float* __restrict__ LP)
{
  __shared__ __align__(16) u32 Pbuf[4][2][320];   // 10 KB: per-wave, per-qi

  const int bid = blockIdx.x;
  const int half = bid & 1;
  const int bh = (bid >> 1) & 15;
  const int qp = bid >> 5;                     // [0,16)
  const int b = bh >> 2, h = bh & 3;
  const int kt0 = half * 32;

  const int tid = threadIdx.x;
  const int w = tid >> 6, lane = tid & 63;
  const int qt0 = qp * 8 + w * 2;              // q-tiles qt0, qt0+1
  const int ln = lane & 15, hb = lane >> 4;

  // ---- Q hi fragments (pre-scaled by 0.125*log2e), per q-tile ----
  short8 qf[2][2];
#pragma unroll
  for (int qi = 0; qi < 2; ++qi) {
    const int base = ((b * H_ + h) * N_ + (qt0 + qi) * 16 + ln) * DH_;
    qf[qi][0] = *(const short8*)&qhg[base + hb * 8];
    qf[qi][1] = *(const short8*)&qhg[base + 32 + hb * 8];
  }

  // per-lane fragment bases (lane*8 folded; per-tile offset = kt*2048)
  const u16* Kt0 = kfg + (size_t)((b * H_ + h) * 64) * 2048 + lane * 8;
  const u16* Vt0 = vfg + (size_t)((b * H_ + h) * 64) * 2048 + lane * 8;
  const u16* Bt0 = biasF + (size_t)((b * 128 + qt0) * 64) * 512 + lane * 8;
  const u16* Bt1 = Bt0 + (size_t)64 * 512;     // q-tile qt0+1

  short8 ones;
#pragma unroll
  for (int i = 0; i < 8; ++i) ones[i] = (short)0x3F80;   // bf16 1.0

  f32x4 O[2][4] = {};      // lane holds O[qi][d=j2*16+hb*4+r][q=ln]
  f32x4 l_acc[2] = {};     // all entries = l(q=ln)
  float m_run[2] = {NEGINF, NEGINF};

  short8 KA[4], KB[4];
  short8 bA[2], bB[2];
  f32x4 dA[2][2], dB[2][2];     // S-stage outputs (logits), per tile buffer
  float pA[2], pB[2];           // S-stage pmax

  auto loadK = [&](short8 (&K)[4], short8 (&bb)[2], int kt) {
#pragma unroll
    for (int i = 0; i < 4; ++i)
      K[i] = *(const short8*)&Kt0[kt * 2048 + i * 512];
    bb[0] = *(const short8*)&Bt0[kt * 512];
    bb[1] = *(const short8*)&Bt1[kt * 512];
  };

  // S: QK^T (bias acc-init) + pmax tree + cross-lane max. No m_run dep.
  auto stageS = [&](const short8 (&K)[4], const short8 (&bb)[2],
                    f32x4 (&dd)[2][2], float (&pm)[2]) {
#pragma unroll
    for (int qi = 0; qi < 2; ++qi) {
#pragma unroll
      for (int j = 0; j < 2; ++j)
#pragma unroll
        for (int r = 0; r < 4; ++r)
          dd[qi][j][r] =
              (float)__builtin_bit_cast(_Float16, (u16)bb[qi][j * 4 + r]);
      __builtin_amdgcn_s_setprio(1);
#pragma unroll
      for (int kc = 0; kc < 2; ++kc)
#pragma unroll
        for (int j = 0; j < 2; ++j)
          dd[qi][j] = MFMA16(K[kc * 2 + j], qf[qi][kc], dd[qi][j]);
      __builtin_amdgcn_s_setprio(0);
      float mx = fmaxf(fmaxf(fmaxf(dd[qi][0][0], dd[qi][0][1]),
                             fmaxf(dd[qi][0][2], dd[qi][0][3])),
                       fmaxf(fmaxf(dd[qi][1][0], dd[qi][1][1]),
                             fmaxf(dd[qi][1][2], dd[qi][1][3])));
      mx = fmaxf(mx, __shfl_xor(mx, 16));
      mx = fmaxf(mx, __shfl_xor(mx, 32));
      pm[qi] = mx;
    }
  };

  // F: m-update (defer-max), exp2, pack, P-exchange -> pf, fac, rs.
  auto stageF = [&](const f32x4 (&dd)[2][2], const float (&pm)[2],
                    short8 (&pf)[2], float (&fac)[2], int (&rs)[2]) {
#pragma unroll
    for (int qi = 0; qi < 2; ++qi) {
      rs[qi] = __any(pm[qi] > m_run[qi] + DEFER_THR) ? 1 : 0;
      fac[qi] = 1.0f;
      if (rs[qi]) {
        const float mn = fmaxf(m_run[qi], pm[qi]);
        fac[qi] = exp2f(m_run[qi] - mn);
        m_run[qi] = mn;
      }
      float p[2][4];
#pragma unroll
      for (int j = 0; j < 2; ++j)
#pragma unroll
        for (int r = 0; r < 4; ++r)
          p[j][r] = exp2f(dd[qi][j][r] - m_run[qi]);
      u32* Pw = &Pbuf[w][qi][0];
#pragma unroll
      for (int j = 0; j < 2; ++j) {
        uint2 wv;
        wv.x = cvtpk(p[j][0], p[j][1]);
        wv.y = cvtpk(p[j][2], p[j][3]);
        *(uint2*)&Pw[ln * 20 + j * 8 + hb * 2] = wv;  // k = j*16+hb*4+{0..3}
      }
      pf[qi] = *(const short8*)&Pw[ln * 20 + hb * 4];
    }
  };

  // P: O-rescale (wave-uniform branch) + PV + l via ones-MFMA.
  auto stageP = [&](const short8 (&Vc)[4], const short8 (&pf)[2],
                    const float (&fac)[2], const int (&rs)[2]) {
#pragma unroll
    for (int qi = 0; qi < 2; ++qi) {
      if (rs[qi]) {
#pragma unroll
        for (int j2 = 0; j2 < 4; ++j2) {
          O[qi][j2][0] *= fac[qi]; O[qi][j2][1] *= fac[qi];
          O[qi][j2][2] *= fac[qi]; O[qi][j2][3] *= fac[qi];
        }
        l_acc[qi][0] *= fac[qi]; l_acc[qi][1] *= fac[qi];
        l_acc[qi][2] *= fac[qi]; l_acc[qi][3] *= fac[qi];
      }
      __builtin_amdgcn_s_setprio(1);
#pragma unroll
      for (int j2 = 0; j2 < 4; ++j2)
        O[qi][j2] = MFMA16(Vc[j2], pf[qi], O[qi][j2]);
      l_acc[qi] = MFMA16(ones, pf[qi], l_acc[qi]);
      __builtin_amdgcn_s_setprio(0);
    }
  };

  // ---- prologue: K/bias for tiles kt0, kt0+1; S(0) ----
  loadK(KA, bA, kt0);
  loadK(KB, bB, kt0 + 1);
  stageS(KA, bA, dA, pA);

  for (int it = 0; it < 32; it += 2) {
    // ---- tile t = kt0+it: S-results in dA/pA; K(t+1) in KB/bB ----
    {
      short8 Vc[4];
#pragma unroll
      for (int i = 0; i < 4; ++i)
        Vc[i] = *(const short8*)&Vt0[(kt0 + it) * 2048 + i * 512];
      loadK(KA, bA, kt0 + ((it + 2) & 31));    // prefetch K(t+2) into A
      short8 pf[2]; float fac[2]; int rs[2];
      stageF(dA, pA, pf, fac, rs);
      stageS(KB, bB, dB, pB);                  // S(t+1)
      stageP(Vc, pf, fac, rs);                 // P(t)
    }
    // ---- tile t+1: S-results in dB/pB; K(t+2) in KA/bA ----
    {
      short8 Vc[4];
#pragma unroll
      for (int i = 0; i < 4; ++i)
        Vc[i] = *(const short8*)&Vt0[(kt0 + it + 1) * 2048 + i * 512];
      loadK(KB, bB, kt0 + ((it + 3) & 31));    // prefetch K(t+3) into B
      short8 pf[2]; float fac[2]; int rs[2];
      stageF(dB, pB, pf, fac, rs);
      stageS(KA, bA, dA, pA);                  // S(t+2) (last iter: unused)
      stageP(Vc, pf, fac, rs);                 // P(t+1)
    }
  }

  // ---- epilogue: write unnormalized partial O + per-q m,l ----
#pragma unroll
  for (int qi = 0; qi < 2; ++qi) {
    const int gg = (b * H_ + h) * 128 + qt0 + qi;    // [0, 2048)
    const int g  = gg * 2 + half;                    // MP/LP index
    float* Opg = (half ? Op1 : Op0) + (size_t)gg * 1024;
#pragma unroll
    for (int j2 = 0; j2 < 4; ++j2)
      *(f32x4*)&Opg[ln * 64 + j2 * 16 + hb * 4] = O[qi][j2];
    if (hb == 0) {
      MP[g * 16 + ln] = m_run[qi];
      LP[g * 16 + ln] = l_acc[qi][0];
    }
  }
}

// ---------------------------------------------------------------------------
// Kernel 3b: combine the two kv-halves, normalize, write split-bf16 attn-out.
// grid 1024 x 256; thread -> (row, 8 cols).
// ---------------------------------------------------------------------------
__global__ __launch_bounds__(256) void k_comb(
    const float* __restrict__ Op0, const float* __restrict__ Op1,
    const float* __restrict__ MP, const float* __restrict__ LP,
    u16* __restrict__ ah, u16* __restrict__ al)
{
  const int i = blockIdx.x * 256 + threadIdx.x;   // [0, 262144)
  const int row = i >> 5, cg = i & 31;
  const int c0 = cg * 8, h = c0 >> 6, d0 = c0 & 63;
  const int b = row >> 11, nn = row & 2047, qt = nn >> 4, q = nn & 15;
  const int gg = (b * H_ + h) * 128 + qt;
  const int g0 = gg * 2;

  const float m1 = MP[g0 * 16 + q],       m2 = MP[(g0 + 1) * 16 + q];
  const float l1 = LP[g0 * 16 + q],       l2 = LP[(g0 + 1) * 16 + q];
  const float mm = fmaxf(m1, m2);
  const float f1 = exp2f(m1 - mm), f2 = exp2f(m2 - mm);
  const float inv = 1.0f / (l1 * f1 + l2 * f2);

  const float* p1 = Op0 + (size_t)gg * 1024 + q * 64 + d0;
  const float* p2 = Op1 + (size_t)gg * 1024 + q * 64 + d0;
  const f32x4 a1 = *(const f32x4*)p1, b1 = *(const f32x4*)(p1 + 4);
  const f32x4 a2 = *(const f32x4*)p2, b2 = *(const f32x4*)(p2 + 4);

  u16v8 hh, ll;
#pragma unroll
  for (int e = 0; e < 4; ++e) {
    const float v = (a1[e] * f1 + a2[e] * f2) * inv;
    split2(v, &hh.v[e], &ll.v[e]);
  }
#pragma unroll
  for (int e = 0; e < 4; ++e) {
    const float v = (b1[e] * f1 + b2[e] * f2) * inv;
    split2(v, &hh.v[e + 4], &ll.v[e + 4]);
  }
  *(u16v8*)&ah[row * DIMX + c0] = hh;
  *(u16v8*)&al[row * DIMX + c0] = ll;
}

// ---------------------------------------------------------------------------
// Kernel 4: out = aout @ Wout + b_out, LDS-staged. M=8192, N=256, K=256.
// grid (4, 64): colb = bx*64; 2 M-subtiles per block; B hi+lo in 64KB LDS.
// ---------------------------------------------------------------------------
__global__ __launch_bounds__(256) void k_out(
    const u16* __restrict__ ahg, const u16* __restrict__ alg,
    const u16* __restrict__ wh, const u16* __restrict__ wl,
    const float* __restrict__ bout, float* __restrict__ out)
{
  __shared__ __align__(16) u16 BhL[64 * 256];   // 32 KB, swizzled
  __shared__ __align__(16) u16 BlL[64 * 256];   // 32 KB

  const int tid = threadIdx.x;
  const int w = tid >> 6, lane = tid & 63;
  const int ln = lane & 15, hb = lane >> 4;
  const int colb = blockIdx.x * 64;

  // ---- stage B (hi+lo) into LDS ----
  {
    short8 sb[16];
#pragma unroll
    for (int it = 0; it < 8; ++it) {
      const int c = it * 8 + (tid >> 5), k8 = tid & 31;
      sb[it]     = *(const short8*)&wh[(colb + c) * 256 + k8 * 8];
      sb[8 + it] = *(const short8*)&wl[(colb + c) * 256 + k8 * 8];
    }
#pragma unroll
    for (int it = 0; it < 8; ++it) {
      const int c = it * 8 + (tid >> 5), k8 = tid & 31;
      const int le = c * 256 + ((k8 * 8) ^ ((c & 7) << 3));
      *(short8*)&BhL[le] = sb[it];
      *(short8*)&BlL[le] = sb[8 + it];
    }
  }
  __syncthreads();

#pragma unroll
  for (int st = 0; st < 2; ++st) {
    const int mtile = blockIdx.y * 2 + st;
    const int arow = mtile * 64 + w * 16 + ln;

    short8 a_h8[8], a_l8[8];
#pragma unroll
    for (int ks = 0; ks < 8; ++ks) {
      a_h8[ks] = *(const short8*)&ahg[arow * 256 + ks * 32 + hb * 8];
      a_l8[ks] = *(const short8*)&alg[arow * 256 + ks * 32 + hb * 8];
    }

    f32x4 acc[4] = {};
#pragma unroll
    for (int ks = 0; ks < 8; ++ks) {
      const int k0 = ks * 32 + hb * 8;
#pragma unroll
      for (int j = 0; j < 4; ++j) {
        const int c = j * 16 + ln;
        const int le = c * 256 + (k0 ^ ((c & 7) << 3));
        const short8 b_h = *(const short8*)&BhL[le];
        const short8 b_l = *(const short8*)&BlL[le];
        acc[j] = MFMA16(a_h8[ks], b_h, acc[j]);
        acc[j] = MFMA16(a_l8[ks], b_h, acc[j]);
        acc[j] = MFMA16(a_h8[ks], b_l, acc[j]);
      }
    }

    const int mbase = mtile * 64 + w * 16 + hb * 4;
#pragma unroll
    for (int j = 0; j < 4; ++j) {
      const int c = colb + j * 16 + ln;
      const float bb = bout[c];
#pragma unroll
      for (int r = 0; r < 4; ++r)
        out[(mbase + r) * 256 + c] = acc[j][r] + bb;
    }
  }
}

// ---------------------------------------------------------------------------
extern "C" void kernel_launch(void* const* d_in, const int* in_sizes, int n_in,
                              void* d_out, int out_size, void* d_ws, size_t ws_size,
                              hipStream_t stream)
{
  (void)in_sizes; (void)n_in; (void)out_size; (void)ws_size;
  const float* x    = (const float*)d_in[0];
  const int*   mask = (const int*)d_in[1];
  const float* spat = (const float*)d_in[2];
  const float* wq   = (const float*)d_in[3];
  const float* wo   = (const float*)d_in[4];
  const float* bout = (const float*)d_in[5];
  float* out = (float*)d_out;

  char* ws = (char*)d_ws;
  size_t o = 0;
  auto alloc = [&](size_t bytes) -> char* {
    char* p = ws + o;
    o += (bytes + 255) & ~(size_t)255;
    return p;
  };
  u16* xh  = (u16*)alloc((size_t)M_ * 256 * 2);   // 4 MB  \ Op0 alias (8 MB)
  u16* xl  = (u16*)alloc((size_t)M_ * 256 * 2);   // 4 MB  /
  u16* wqh = (u16*)alloc((size_t)768 * 256 * 2);  // 384KB -> MP alias (256KB)
  u16* wql = (u16*)alloc((size_t)768 * 256 * 2);  // 384KB -> LP alias (256KB)
  u16* woh = (u16*)alloc((size_t)256 * 256 * 2);
  u16* wol = (u16*)alloc((size_t)256 * 256 * 2);
  u16* qh  = (u16*)alloc((size_t)16 * N_ * DH_ * 2);
  u16* ql  = (u16*)alloc((size_t)16 * N_ * DH_ * 2);
  u16* kf  = (u16*)alloc((size_t)16 * N_ * DH_ * 2);
  u16* vf  = (u16*)alloc((size_t)16 * N_ * DH_ * 2);
  u16* ah  = (u16*)alloc((size_t)M_ * 256 * 2);
  u16* al  = (u16*)alloc((size_t)M_ * 256 * 2);
  u16* biasF = (u16*)alloc((size_t)4 * 128 * 64 * 512 * 2);  // 33.5 MB fp16

  // Safe scratch aliases (sizes verified, R9-proven):
  //  Op0 (8,388,608 B) <- xh+xl (contiguous, dead after k_qkv)
  //  Op1 (8,388,608 B) <- d_out (fully overwritten by k_out)
  //  MP/LP (262,144 B) <- wqh / wql (393,216 B each, dead after k_qkv)
  float* Op0 = (float*)xh;
  float* Op1 = out;
  float* MP  = (float*)wqh;
  float* LP  = (float*)wql;

  hipLaunchKernelGGL(k_prep, dim3(7168), dim3(256), 0, stream,
                     mask, spat, x, wq, wo, biasF,
                     xh, xl, wqh, wql, woh, wol);
  hipLaunchKernelGGL(k_qkv, dim3(12, 64), dim3(256), 0, stream,
                     xh, xl, wqh, wql, qh, ql, kf, vf);
  hipLaunchKernelGGL(k_attn, dim3(512), dim3(256), 0, stream,
                     qh, kf, vf, biasF, Op0, Op1, MP, LP);
  hipLaunchKernelGGL(k_comb, dim3(1024), dim3(256), 0, stream,
                     Op0, Op1, MP, LP, ah, al);
  hipLaunchKernelGGL(k_out, dim3(4, 64), dim3(256), 0, stream,
                     ah, al, woh, wol, bout, out);
}